// Round 4
// baseline (297.633 us; speedup 1.0000x reference)
//
#include <hip/hip_runtime.h>

#define DIMN 1024
#define TN 4096
#define BN 8
#define CBN 4096
#define BTN (BN*TN)
#define OUT_ELEMS (BN*DIMN*TN)

typedef float fx4 __attribute__((ext_vector_type(4)));
typedef float fx2 __attribute__((ext_vector_type(2)));

// ws layout (float offsets)
#define WS_WINT 0          // W_in^T scaled: [d][8], 8192 floats
#define WS_WOUT 8192       // W_out scaled: [o][8], 8192 floats
#define WS_C2   49152      // h = -0.5*sum(c_n^2) per code, 4096 floats
#define WS_CNP  53248      // paired normalized codebook [j/2][8dims][2], 32768 floats
#define WS_LOSS 86016      // 8 floats (per-batch loss accum)
#define WS_CNT  86024      // completion counter (uint bits)

// k_mega LDS (floats), total 13056 = 52224 B -> 2 blocks/CU at 512 thr = 16 waves/CU
// regionA [0,8192): phase Z = W_in^T[1024][8]; out phase = W_out half-swizzled [1024][8]
// rows [8192, 8192+64*68): per-t 68-float rows:
//   phase Z: partial p at [p*8, p*8+8), p=0..7
//   post-fold: [0,8)=z_e, [8,16)=e_n, [16,32)=b_out stage, [32,48)=cand[8 waves][2]
// LZQ [12544,13056): z_q transposed [8][64]
#define LROWS_F 8192
#define LROW    68
#define LZQ_F   12544
#define LDS_TOT 13056

__device__ __forceinline__ float dot4(float4 a, float4 b) {
    float d = a.x * b.x;
    d = fmaf(a.y, b.y, d);
    d = fmaf(a.z, b.z, d);
    d = fmaf(a.w, b.w, d);
    return d;
}
__device__ __forceinline__ void add4(float4& a, float4 b) {
    a.x += b.x; a.y += b.y; a.z += b.z; a.w += b.w;
}
__device__ __forceinline__ fx2 lo2(fx4 v) { return __builtin_shufflevector(v, v, 0, 1); }
__device__ __forceinline__ fx2 hi2(fx4 v) { return __builtin_shufflevector(v, v, 2, 3); }
__device__ __forceinline__ fx2 splat2(float x) { fx2 r; r.x = x; r.y = x; return r; }
__device__ __forceinline__ fx2 fma2(fx2 a, fx2 b, fx2 c) { return __builtin_elementwise_fma(a, b, c); }
__device__ __forceinline__ fx2 max2(fx2 a, fx2 b) { return __builtin_elementwise_max(a, b); }
__device__ __forceinline__ fx2 min2(fx2 a, fx2 b) { return __builtin_elementwise_min(a, b); }
__device__ __forceinline__ fx4 cat4(fx2 a, fx2 b) { return __builtin_shufflevector(a, b, 0, 1, 2, 3); }

// ---------------- K0: prep weights / paired codebook / zero loss+counter ----------------
__global__ __launch_bounds__(256) void k0_prep(
    const float* __restrict__ v_in, const float* __restrict__ g_in,
    const float* __restrict__ codebook, const float* __restrict__ v_out,
    const float* __restrict__ g_out, float* __restrict__ ws) {
    __shared__ float sred[5];
    int blk = blockIdx.x, tid = threadIdx.x;
    if (blk < 8) {
        int o = blk;
        const float* v = v_in + o * DIMN;
        float4 x = *(const float4*)(v + tid * 4);
        float p = x.x * x.x + x.y * x.y + x.z * x.z + x.w * x.w;
        for (int off = 32; off >= 1; off >>= 1) p += __shfl_down(p, off, 64);
        if ((tid & 63) == 0) sred[tid >> 6] = p;
        __syncthreads();
        if (tid == 0) {
            float tot = sred[0] + sred[1] + sred[2] + sred[3];
            sred[4] = g_in[o] / sqrtf(tot);
        }
        __syncthreads();
        float s = sred[4];
        ws[WS_WINT + (tid * 4 + 0) * 8 + o] = x.x * s;
        ws[WS_WINT + (tid * 4 + 1) * 8 + o] = x.y * s;
        ws[WS_WINT + (tid * 4 + 2) * 8 + o] = x.z * s;
        ws[WS_WINT + (tid * 4 + 3) * 8 + o] = x.w * s;
    } else if (blk < 12) {
        int r = (blk - 8) * 256 + tid;
        const float* v = v_out + r * 8;
        float4 a = *(const float4*)v;
        float4 b = *(const float4*)(v + 4);
        float n2 = dot4(a, a) + dot4(b, b);
        float s = g_out[r] / sqrtf(n2);
        *(float4*)(ws + WS_WOUT + r * 8)     = make_float4(a.x*s, a.y*s, a.z*s, a.w*s);
        *(float4*)(ws + WS_WOUT + r * 8 + 4) = make_float4(b.x*s, b.y*s, b.z*s, b.w*s);
    } else if (blk < 28) {
        int j = (blk - 12) * 256 + tid;
        const float* c = codebook + j * 8;
        float4 a = *(const float4*)c;
        float4 b = *(const float4*)(c + 4);
        float n2 = dot4(a, a) + dot4(b, b);
        float inv = 1.0f / fmaxf(sqrtf(n2), 1e-12f);
        float na[8] = {a.x*inv, a.y*inv, a.z*inv, a.w*inv,
                       b.x*inv, b.y*inv, b.z*inv, b.w*inv};
        // paired layout: pair j>>1, dim i, slot j&1
        float* dst = ws + WS_CNP + (size_t)(j >> 1) * 16 + (j & 1);
        #pragma unroll
        for (int i = 0; i < 8; i++) dst[i * 2] = na[i];
        float h = 0.0f;
        #pragma unroll
        for (int i = 0; i < 8; i++) h = fmaf(na[i], na[i], h);
        ws[WS_C2 + j] = -0.5f * h;                 // argmin dist == argmax dot+h
    } else {
        if (tid < 9) ws[WS_LOSS + tid] = 0.0f;     // 8 loss slots + counter
    }
}

// ---------------- K_mega: z_e + search + merge + loss + idx + out-projection ----------------
// grid 512 = (b = blk>>6, 64-t tile = blk&63), 512 threads, 52.2 KB LDS -> 2 blocks/CU.
__global__ __launch_bounds__(512, 4) void k_mega(
    const float* __restrict__ z, const float* __restrict__ b_in,
    const float* __restrict__ codebook, const float* __restrict__ b_out,
    float* __restrict__ dout, float* __restrict__ ws) {
    __shared__ float sp[LDS_TOT];
    int tid = threadIdx.x, blk = blockIdx.x;
    int b = blk >> 6;
    int t0 = (blk & 63) * 64;

    // ---- stage W_in^T [1024][8] into region A (all 512 threads) ----
    #pragma unroll
    for (int i = 0; i < 4; i++) {
        int f4 = tid + i * 512;
        *(fx4*)(sp + f4 * 4) = *(const fx4*)(ws + WS_WINT + f4 * 4);
    }
    __syncthreads();

    // ---- phase Z (tid<256): proven k1a-identical chains, fx2-packed fma ----
    if (tid < 256) {
        int p = tid >> 5, tpair = tid & 31;
        int tA = tpair * 2;
        const float* zp = z + ((size_t)(b * DIMN + p * 128)) * TN + t0 + tA;
        fx2 a0aL = splat2(0.f), a0aH = splat2(0.f), a0bL = splat2(0.f), a0bH = splat2(0.f);
        fx2 a1aL = splat2(0.f), a1aH = splat2(0.f), a1bL = splat2(0.f), a1bH = splat2(0.f);
        #pragma unroll 8
        for (int dd = 0; dd < 128; ++dd) {
            fx2 zv = __builtin_nontemporal_load((const fx2*)(zp + (size_t)dd * TN));
            const float* wv = sp + (p * 128 + dd) * 8;   // half-wave-uniform -> broadcast
            fx4 w0 = *(const fx4*)wv;
            fx4 w1 = *(const fx4*)(wv + 4);
            fx2 zx = splat2(zv.x), zy = splat2(zv.y);
            a0aL = fma2(lo2(w0), zx, a0aL); a0aH = fma2(hi2(w0), zx, a0aH);
            a0bL = fma2(lo2(w1), zx, a0bL); a0bH = fma2(hi2(w1), zx, a0bH);
            a1aL = fma2(lo2(w0), zy, a1aL); a1aH = fma2(hi2(w0), zy, a1aH);
            a1bL = fma2(lo2(w1), zy, a1bL); a1bH = fma2(hi2(w1), zy, a1bH);
        }
        float* q0 = sp + LROWS_F + tA * LROW + p * 8;
        *(fx4*)(q0)     = cat4(a0aL, a0aH);
        *(fx4*)(q0 + 4) = cat4(a0bL, a0bH);
        float* q1 = sp + LROWS_F + (tA + 1) * LROW + p * 8;
        *(fx4*)(q1)     = cat4(a1aL, a1aH);
        *(fx4*)(q1 + 4) = cat4(a1bL, a1bH);
    }
    __syncthreads();

    // ---- fold + normalize (tid<64): bitwise-identical ascending-p fold ----
    if (tid < 64) {
        int t = tid;
        float4 za = *(const float4*)(b_in);
        float4 zb = *(const float4*)(b_in + 4);
        #pragma unroll
        for (int p = 0; p < 8; p++) {
            const float* pp = sp + LROWS_F + t * LROW + p * 8;
            add4(za, *(const float4*)(pp));
            add4(zb, *(const float4*)(pp + 4));
        }
        float* row = sp + LROWS_F + t * LROW;
        *(float4*)(row)     = za;                  // z_e at [0,8)
        *(float4*)(row + 4) = zb;
        float inv = 1.0f / fmaxf(sqrtf(dot4(za, za) + dot4(zb, zb)), 1e-12f);
        *(float4*)(row + 8)  = make_float4(za.x*inv, za.y*inv, za.z*inv, za.w*inv);  // e_n [8,16)
        *(float4*)(row + 12) = make_float4(zb.x*inv, zb.y*inv, zb.z*inv, zb.w*inv);
    }
    __syncthreads();

    // ---- search: 32 code-octets x 16 t-groups x 4 t; packed even/odd pairs ----
    int co = tid >> 4, tg = tid & 15;
    float en[4][8];
    #pragma unroll
    for (int k = 0; k < 4; k++) {
        const float* rp = sp + LROWS_F + (tg * 4 + k) * LROW + 8;
        fx4 u = *(const fx4*)rp;
        fx4 v = *(const fx4*)(rp + 4);
        en[k][0]=u.x; en[k][1]=u.y; en[k][2]=u.z; en[k][3]=u.w;
        en[k][4]=v.x; en[k][5]=v.y; en[k][6]=v.z; en[k][7]=v.w;
    }
    fx2 bs[4]; int bje[4], bjo[4];
    #pragma unroll
    for (int k = 0; k < 4; k++) { bs[k] = splat2(-3.4e38f); bje[k] = 0; bjo[k] = 1; }
    #pragma unroll 1
    for (int ci = 0; ci < 16; ++ci) {
        int j0 = ci * 256 + co * 8;                // my 8 codes = 4 pairs, ascending
        const float* cg = ws + WS_CNP + (size_t)j0 * 8;
        #pragma unroll
        for (int pp = 0; pp < 4; ++pp) {
            fx4 cA = *(const fx4*)(cg + pp * 16);
            fx4 cB = *(const fx4*)(cg + pp * 16 + 4);
            fx4 cC = *(const fx4*)(cg + pp * 16 + 8);
            fx4 cD = *(const fx4*)(cg + pp * 16 + 12);
            fx2 h2 = *(const fx2*)(ws + WS_C2 + j0 + pp * 2);
            int jE = j0 + pp * 2;
            #pragma unroll
            for (int k = 0; k < 4; k++) {
                fx2 s = h2;                         // same chain per half as proven scalar
                s = fma2(splat2(en[k][0]), lo2(cA), s);
                s = fma2(splat2(en[k][1]), hi2(cA), s);
                s = fma2(splat2(en[k][2]), lo2(cB), s);
                s = fma2(splat2(en[k][3]), hi2(cB), s);
                s = fma2(splat2(en[k][4]), lo2(cC), s);
                s = fma2(splat2(en[k][5]), hi2(cC), s);
                s = fma2(splat2(en[k][6]), lo2(cD), s);
                s = fma2(splat2(en[k][7]), hi2(cD), s);
                bool cE = s.x > bs[k].x;            // strict >: first-max per parity
                bool cO = s.y > bs[k].y;
                bs[k] = max2(bs[k], s);
                if (cE) bje[k] = jE;
                if (cO) bjo[k] = jE + 1;
            }
        }
    }
    // combine odd into even (global first-argmax: > or ==&&lower j)
    float bsF[4]; int bjF[4];
    #pragma unroll
    for (int k = 0; k < 4; k++) {
        bsF[k] = bs[k].x; bjF[k] = bje[k];
        if (bs[k].y > bsF[k] || (bs[k].y == bsF[k] && bjo[k] < bjF[k])) {
            bsF[k] = bs[k].y; bjF[k] = bjo[k];
        }
    }
    // in-wave butterfly across the 4 co's of this wave
    #pragma unroll
    for (int st = 16; st <= 32; st <<= 1) {
        #pragma unroll
        for (int k = 0; k < 4; k++) {
            float os = __shfl_xor(bsF[k], st, 64);
            int   oj = __shfl_xor(bjF[k], st, 64);
            if (os > bsF[k] || (os == bsF[k] && oj < bjF[k])) { bsF[k] = os; bjF[k] = oj; }
        }
    }
    if ((tid & 63) < 16) {                          // one lane per t-group publishes
        int w = tid >> 6;
        #pragma unroll
        for (int k = 0; k < 4; k++)
            *(fx2*)(sp + LROWS_F + (tg * 4 + k) * LROW + 32 + w * 2) =
                (fx2){bsF[k], __int_as_float(bjF[k])};
    }
    __syncthreads();

    // ---- merge 8 wave-cands + gather + loss (tid<64) || stage W_out/b_out (tid>=64) ----
    if (tid < 64) {
        int t = tid;
        const float* crow = sp + LROWS_F + t * LROW + 32;
        fx2 c0 = *(const fx2*)(crow);
        float best = c0.x; int idx = __float_as_int(c0.y);
        #pragma unroll
        for (int w2 = 1; w2 < 8; w2++) {
            fx2 cw = *(const fx2*)(crow + w2 * 2);
            int j2 = __float_as_int(cw.y);
            if (cw.x > best || (cw.x == best && j2 < idx)) { best = cw.x; idx = j2; }
        }
        dout[(size_t)OUT_ELEMS + b * TN + t0 + t] = (float)idx;
        const float* cq = codebook + (size_t)idx * 8;     // raw (un-normalized)
        float4 qa = *(const float4*)cq, qb = *(const float4*)(cq + 4);
        sp[LZQ_F + 0*64 + t] = qa.x; sp[LZQ_F + 1*64 + t] = qa.y;
        sp[LZQ_F + 2*64 + t] = qa.z; sp[LZQ_F + 3*64 + t] = qa.w;
        sp[LZQ_F + 4*64 + t] = qb.x; sp[LZQ_F + 5*64 + t] = qb.y;
        sp[LZQ_F + 6*64 + t] = qb.z; sp[LZQ_F + 7*64 + t] = qb.w;
        const float* row = sp + LROWS_F + t * LROW;
        float4 za = *(const float4*)(row);
        float4 zb = *(const float4*)(row + 4);
        float4 da = make_float4(za.x-qa.x, za.y-qa.y, za.z-qa.z, za.w-qa.w);
        float4 db = make_float4(zb.x-qb.x, zb.y-qb.y, zb.z-qb.z, zb.w-qb.w);
        float l = dot4(da, da) + dot4(db, db);
        for (int off = 32; off >= 1; off >>= 1) l += __shfl_down(l, off, 64);
        if (t == 0) atomicAdd(ws + WS_LOSS + b, l);
    } else {
        int i = tid - 64;                           // 448 threads
        #pragma unroll
        for (int r = 0; r < 5; r++) {               // W_out: 2048 float4, half-swizzled
            int f4 = r * 448 + i;
            if (f4 < 2048) {
                fx4 v = *(const fx4*)(ws + WS_WOUT + f4 * 4);
                int o = f4 >> 1, h = f4 & 1;
                int tog = (o >> 6) & 1;
                *(fx4*)(sp + o * 8 + ((h ^ tog) << 2)) = v;
            }
        }
        #pragma unroll
        for (int r = 0; r < 3; r++) {               // b_out into row slots [16,32)
            int e = r * 448 + i;
            if (e < 1024) sp[LROWS_F + (e & 63) * LROW + 16 + (e >> 6)] = b_out[e];
        }
    }
    __syncthreads();

    // ---- out-projection: thread (t4 = tid&15, og = tid>>5... ) 4 t x 32 o ----
    {
        int t4 = tid & 15, og = tid >> 4;           // og 0..31, 32 o's each
        fx4 zr[8];
        #pragma unroll
        for (int c = 0; c < 8; c++) zr[c] = *(const fx4*)(sp + LZQ_F + c * 64 + t4 * 4);
        fx2 cmn = splat2(-8.f), cmx = splat2(8.f);
        size_t obase = ((size_t)(b * DIMN + og * 32)) * TN + (size_t)(t0 + t4 * 4);
        for (int k = 0; k < 32; k++) {
            int o = og * 32 + k;
            int tog = (o >> 6) & 1;
            fx4 wa = *(const fx4*)(sp + o * 8 + (tog << 2));
            fx4 wb = *(const fx4*)(sp + o * 8 + ((tog ^ 1) << 2));
            float bo = sp[LROWS_F + (o & 63) * LROW + 16 + (o >> 6)];
            fx2 accL = splat2(bo), accH = splat2(bo);
            float wcv[8] = {wa.x, wa.y, wa.z, wa.w, wb.x, wb.y, wb.z, wb.w};
            #pragma unroll
            for (int c = 0; c < 8; c++) {
                fx2 ws2 = splat2(wcv[c]);
                accL = fma2(ws2, lo2(zr[c]), accL);
                accH = fma2(ws2, hi2(zr[c]), accH);
            }
            accL = min2(max2(accL, cmn), cmx);
            accH = min2(max2(accH, cmn), cmx);
            fx4 st = cat4(accL, accH);
            __builtin_nontemporal_store(st, (fx4*)(dout + obase + (size_t)k * TN));
        }
    }

    // ---- last block finalizes losses (device-scope counter pattern, proven) ----
    if (tid == 0) {
        __threadfence();
        unsigned int old = atomicAdd((unsigned int*)(ws + WS_CNT), 1u);
        if (old == 511u) {
            #pragma unroll
            for (int i = 0; i < 8; i++) {
                float v = atomicAdd(ws + WS_LOSS + i, 0.0f);   // coherent read
                dout[(size_t)OUT_ELEMS + BTN + i] = v * (1.25f / 32768.0f);
            }
        }
    }
}

extern "C" void kernel_launch(void* const* d_in, const int* in_sizes, int n_in,
                              void* d_out, int out_size, void* d_ws, size_t ws_size,
                              hipStream_t stream) {
    (void)in_sizes; (void)n_in; (void)out_size; (void)ws_size;
    const float* z        = (const float*)d_in[0];
    const float* v_in     = (const float*)d_in[1];
    const float* g_in     = (const float*)d_in[2];
    const float* b_in     = (const float*)d_in[3];
    const float* codebook = (const float*)d_in[4];
    const float* v_out    = (const float*)d_in[5];
    const float* g_out    = (const float*)d_in[6];
    const float* b_out    = (const float*)d_in[7];
    float* out            = (float*)d_out;
    float* ws             = (float*)d_ws;

    hipLaunchKernelGGL(k0_prep, dim3(29), dim3(256), 0, stream,
                       v_in, g_in, codebook, v_out, g_out, ws);
    hipLaunchKernelGGL(k_mega, dim3(512), dim3(512), 0, stream,
                       z, b_in, codebook, b_out, out, ws);
}